// Round 5
// baseline (3197.075 us; speedup 1.0000x reference)
//
#include <hip/hip_runtime.h>
#include <hip/hip_bf16.h>

#define SEQL 64
#define BATCH 64
#define HIDDEN 512
#define VOCAB 32000
#define NSTACK 2
#define DEPTH 4
#define SSIZE 64
#define ESIZE 128
#define KCAT 2048  // HIDDEN*4: [emb | hid | sv0 | sv1]

typedef __attribute__((ext_vector_type(8))) short bf16x8;
typedef __attribute__((ext_vector_type(4))) float f32x4;

// workspace layout (bytes, 256-aligned)
#define OFF_HIDF    0u          // float hidF[2][64][512]          = 262144 B
#define OFF_STACKS  262144u     // float stacks[2][64][2][64][128] = 8388608 B
#define OFF_XHI     8650752u    // bf16 Xhi[2][64][2048]           = 524288 B
#define OFF_XLO     9175040u    // bf16 Xlo[2][64][2048]           = 524288 B
#define OFF_WCATHI  9699328u    // bf16 WcatHi[512][2048]          = 2097152 B
#define OFF_WCATLO  11796480u   // bf16 WcatLo[512][2048]          = 2097152 B
#define OFF_HALL    13893632u   // bf16 H_all[4096][512]           = 4194304 B
#define OFF_WOUTB   18087936u   // bf16 Wb[32000][512]             = 32768000 B
#define WS_NEED_PRE (OFF_WOUTB + 32768000u)

__device__ __forceinline__ float sigmoidf_(float x) {
    return 1.f / (1.f + __expf(-x));
}

// split fp32 into bf16 hi + bf16 lo (hi+lo ~ 16-17 mantissa bits of x)
__device__ __forceinline__ void bf16split(float v, __hip_bfloat16& hi, __hip_bfloat16& lo) {
    hi = __float2bfloat16(v);
    lo = __float2bfloat16(v - __bfloat162float(hi));
}

// ---------------------------------------------------------------------------
// prep: pack Wcat (bf16 hi/lo), init X[0] hi/lo, hidF[0], stacks[0]
// ---------------------------------------------------------------------------
__global__ __launch_bounds__(256) void prep_kernel(
    const int* __restrict__ inputs, const float* __restrict__ hidden,
    const float* __restrict__ embedding,
    const float* __restrict__ W_i2h, const float* __restrict__ W_h2h,
    const float* __restrict__ W_s2h, const float* __restrict__ empty_elem,
    __hip_bfloat16* __restrict__ WcatHi, __hip_bfloat16* __restrict__ WcatLo,
    __hip_bfloat16* __restrict__ X0hi, __hip_bfloat16* __restrict__ X0lo,
    float* __restrict__ hidF0, float* __restrict__ stacks0)
{
    const int NT_WCAT   = 512 * 2048;        // 1048576
    const int NT_X0     = 64 * 2048;         // 131072
    const int NT_HIDF   = 64 * 512;          // 32768
    const int NT_STACKS = 64 * 2 * 64 * 128; // 1048576
    const int total = NT_WCAT + NT_X0 + NT_HIDF + NT_STACKS;
    for (int idx = blockIdx.x * 256 + threadIdx.x; idx < total; idx += gridDim.x * 256) {
        int i = idx;
        if (i < NT_WCAT) {
            int h = i >> 11, k = i & 2047;
            float v;
            if (k < 512)       v = W_i2h[h * 512 + k];
            else if (k < 1024) v = W_h2h[h * 512 + (k - 512)];
            else if (k < 1536) v = W_s2h[h * 512 + (k - 1024)];
            else               v = W_s2h[512 * 512 + h * 512 + (k - 1536)];
            __hip_bfloat16 hi, lo; bf16split(v, hi, lo);
            WcatHi[i] = hi; WcatLo[i] = lo;
            continue;
        }
        i -= NT_WCAT;
        if (i < NT_X0) {
            int b = i >> 11, k = i & 2047;
            float v;
            if (k < 512)       v = embedding[(size_t)inputs[b] * 512 + k];
            else if (k < 1024) v = hidden[b * 512 + (k - 512)];
            else               v = empty_elem[(k - 1024) & 127];
            __hip_bfloat16 hi, lo; bf16split(v, hi, lo);
            X0hi[i] = hi; X0lo[i] = lo;
            continue;
        }
        i -= NT_X0;
        if (i < NT_HIDF) { hidF0[i] = hidden[i]; continue; }
        i -= NT_HIDF;
        stacks0[i] = empty_elem[i & 127];
    }
}

// convert W_out fp32 -> bf16 once (only launched when ws_size permits)
__global__ __launch_bounds__(256) void wout_bf16_kernel(
    const float* __restrict__ W_out, __hip_bfloat16* __restrict__ Wb)
{
    const int total = VOCAB * HIDDEN / 4;
    for (int i = blockIdx.x * 256 + threadIdx.x; i < total; i += gridDim.x * 256) {
        float4 v = ((const float4*)W_out)[i];
        __hip_bfloat16 t[4] = {__float2bfloat16(v.x), __float2bfloat16(v.y),
                               __float2bfloat16(v.z), __float2bfloat16(v.w)};
        *(short4*)(&Wb[i * 4]) = *(const short4*)t;
    }
}

// ---------------------------------------------------------------------------
// one recurrence step.  grid = 80 blocks x 256 threads:
//   blocks 0..63  : stack blocks (b = blockIdx) — gates + stack shift (fp32)
//   blocks 64..79 : mid blocks — split-bf16 MFMA [64 x 2048] @ [2048 x 32]
// ---------------------------------------------------------------------------
__global__ __launch_bounds__(256) void step_kernel(
    int t,
    const int* __restrict__ inputs, const float* __restrict__ embedding,
    const float* __restrict__ W_h2a, const float* __restrict__ b_h2a,
    const float* __restrict__ W_h2s, const float* __restrict__ b_h2s,
    const float* __restrict__ b_i2h, const float* __restrict__ b_h2h,
    const float* __restrict__ b_s2h, const float* __restrict__ empty_elem,
    const __hip_bfloat16* __restrict__ WcatHi, const __hip_bfloat16* __restrict__ WcatLo,
    float* __restrict__ hidF, float* __restrict__ stacks,
    __hip_bfloat16* __restrict__ Xhi, __hip_bfloat16* __restrict__ Xlo,
    __hip_bfloat16* __restrict__ H_all, float* __restrict__ out_tail)
{
    const int cur = t & 1, nxt = cur ^ 1;
    const int tid = threadIdx.x;

    if (blockIdx.x < 64) {
        // ---------------- stack block ----------------
        __shared__ float hidL[512];
        __shared__ float actsL[2][3];
        const int b = blockIdx.x;
        const float* hcur = hidF + cur * (64 * 512) + b * 512;
        hidL[tid]       = hcur[tid];
        hidL[tid + 256] = hcur[tid + 256];
        __syncthreads();

        const int n = tid >> 7, e = tid & 127;
        // push_val[e] = sigmoid(hid . W_h2s[n][e] + b_h2s[n][e])   (fp32, pre-update hid)
        const float* wrow = W_h2s + (size_t)(n * 128 + e) * 512;
        float acc = 0.f;
#pragma unroll 4
        for (int k = 0; k < 512; k += 4) {
            float4 w = *(const float4*)(wrow + k);
            acc += w.x * hidL[k] + w.y * hidL[k + 1] + w.z * hidL[k + 2] + w.w * hidL[k + 3];
        }
        float pv = sigmoidf_(acc + b_h2s[n * 128 + e]);

        if (e < 3) {
            const float* ar = W_h2a + (size_t)(n * 3 + e) * 512;
            float a = 0.f;
#pragma unroll 4
            for (int k = 0; k < 512; k += 4) {
                float4 w = *(const float4*)(ar + k);
                a += w.x * hidL[k] + w.y * hidL[k + 1] + w.z * hidL[k + 2] + w.w * hidL[k + 3];
            }
            actsL[n][e] = a + b_h2a[n * 3 + e];
        }
        __syncthreads();

        const float pp = actsL[n][0], po = actsL[n][1], pq = actsL[n][2];
        const float* sc = stacks + cur * (64 * 2 * 64 * 128) + (size_t)((b * 2 + n) * 64) * 128 + e;
        float*       sn = stacks + nxt * (64 * 2 * 64 * 128) + (size_t)((b * 2 + n) * 64) * 128 + e;
        __hip_bfloat16* xsvH = Xhi + nxt * (64 * 2048) + b * 2048 + 1024 + n * 512 + e;
        __hip_bfloat16* xsvL = Xlo + nxt * (64 * 2048) + b * 2048 + 1024 + n * 512 + e;

        // row 0: raw push gate * push_val
        float nv0 = pp * pv;
        sn[0] = nv0;
        { __hip_bfloat16 hi, lo; bf16split(nv0, hi, lo); xsvH[0] = hi; xsvL[0] = lo; }
        // rows 1..62: pp*old[i-1] + po*old[i+1] + pq*old[i]
        float prev = sc[0], curv = sc[128];
        for (int i = 1; i <= 62; ++i) {
            float nextv = sc[(i + 1) * 128];
            float nv = pp * prev + po * nextv + pq * curv;
            sn[i * 128] = nv;
            if (i < 4) { __hip_bfloat16 hi, lo; bf16split(nv, hi, lo);
                         xsvH[i * 128] = hi; xsvL[i * 128] = lo; }
            prev = curv; curv = nextv;
        }
        // row 63: empty element
        sn[63 * 128] = empty_elem[e];

        // prefetch next step's embedding row into X[nxt] (hi/lo)
        if (t + 1 < SEQL) {
            int vidx = inputs[(t + 1) * 64 + b];
            const float* er = embedding + (size_t)vidx * 512;
            __hip_bfloat16* xeH = Xhi + nxt * (64 * 2048) + b * 2048;
            __hip_bfloat16* xeL = Xlo + nxt * (64 * 2048) + b * 2048;
            { __hip_bfloat16 hi, lo; bf16split(er[tid], hi, lo); xeH[tid] = hi; xeL[tid] = lo; }
            { __hip_bfloat16 hi, lo; bf16split(er[tid + 256], hi, lo);
              xeH[tid + 256] = hi; xeL[tid + 256] = lo; }
        }
    } else {
        // ---------------- mid block (split-bf16 MFMA), 32 h-cols per block ----
        __shared__ __align__(16) __hip_bfloat16 Ahi[64 * 64];
        __shared__ __align__(16) __hip_bfloat16 Alo[64 * 64];
        __shared__ __align__(16) __hip_bfloat16 Bhi[32 * 64];
        __shared__ __align__(16) __hip_bfloat16 Blo[32 * 64];
        const int n0 = (blockIdx.x - 64) * 32;
        const __hip_bfloat16* XcH = Xhi + cur * (64 * 2048);
        const __hip_bfloat16* XcL = Xlo + cur * (64 * 2048);
        const int w = tid >> 6, l = tid & 63;
        f32x4 acc[2] = {};

        for (int k0 = 0; k0 < 2048; k0 += 64) {
            __syncthreads();
#pragma unroll
            for (int r = 0; r < 2; ++r) {
                int idx = r * 256 + tid;          // 0..511 chunks of 8 bf16 (A: 64x64)
                int row = idx >> 3, col = (idx & 7) * 8;
                *(bf16x8*)(&Ahi[idx * 8]) = *(const bf16x8*)(XcH + (size_t)row * 2048 + k0 + col);
                *(bf16x8*)(&Alo[idx * 8]) = *(const bf16x8*)(XcL + (size_t)row * 2048 + k0 + col);
            }
            {
                int row = tid >> 3, col = (tid & 7) * 8;  // B: 32x64, 256 chunks
                *(bf16x8*)(&Bhi[tid * 8]) = *(const bf16x8*)(WcatHi + (size_t)(n0 + row) * 2048 + k0 + col);
                *(bf16x8*)(&Blo[tid * 8]) = *(const bf16x8*)(WcatLo + (size_t)(n0 + row) * 2048 + k0 + col);
            }
            __syncthreads();
#pragma unroll
            for (int ks = 0; ks < 2; ++ks) {
                const int ko = ks * 32 + (l >> 4) * 8;
                bf16x8 ah = *(const bf16x8*)(&Ahi[(w * 16 + (l & 15)) * 64 + ko]);
                bf16x8 al = *(const bf16x8*)(&Alo[(w * 16 + (l & 15)) * 64 + ko]);
#pragma unroll
                for (int ni = 0; ni < 2; ++ni) {
                    bf16x8 bh = *(const bf16x8*)(&Bhi[(ni * 16 + (l & 15)) * 64 + ko]);
                    bf16x8 bl = *(const bf16x8*)(&Blo[(ni * 16 + (l & 15)) * 64 + ko]);
                    acc[ni] = __builtin_amdgcn_mfma_f32_16x16x32_bf16(ah, bh, acc[ni], 0, 0, 0);
                    acc[ni] = __builtin_amdgcn_mfma_f32_16x16x32_bf16(ah, bl, acc[ni], 0, 0, 0);
                    acc[ni] = __builtin_amdgcn_mfma_f32_16x16x32_bf16(al, bh, acc[ni], 0, 0, 0);
                }
            }
        }

        // epilogue: bias + sigmoid; write hidF[nxt], X[nxt].hid (hi/lo), H_all[t]
        float* hidN = hidF + nxt * (64 * 512);
        __hip_bfloat16* XnH = Xhi + nxt * (64 * 2048);
        __hip_bfloat16* XnL = Xlo + nxt * (64 * 2048);
#pragma unroll
        for (int ni = 0; ni < 2; ++ni)
#pragma unroll
            for (int r = 0; r < 4; ++r) {
                int bb = w * 16 + (l >> 4) * 4 + r;          // batch row
                int h  = n0 + ni * 16 + (l & 15);            // hidden col
                float bias = b_i2h[h] + b_h2h[h] + b_s2h[h] + b_s2h[512 + h];
                float s = sigmoidf_(acc[ni][r] + bias);
                hidN[bb * 512 + h] = s;
                __hip_bfloat16 shi, slo; bf16split(s, shi, slo);
                XnH[bb * 2048 + 512 + h] = shi;
                XnL[bb * 2048 + 512 + h] = slo;
                H_all[(size_t)(t * 64 + bb) * 512 + h] = shi;
                if (t == SEQL - 1) out_tail[bb * 512 + h] = s;
            }
    }
}

// ---------------------------------------------------------------------------
// output projection: logits = H_all @ W_out^T + b_out  ([4096,512]@[512,32000])
// 128x128 tiles, BK=32, bf16 MFMA 16x16x32.
// PRE=true: B from pre-converted bf16 Wb.  PRE=false: convert fp32 on the fly.
// ---------------------------------------------------------------------------
template <bool PRE>
__global__ __launch_bounds__(256) void gemm_out_kernel(
    const __hip_bfloat16* __restrict__ H_all, const float* __restrict__ W_out,
    const __hip_bfloat16* __restrict__ Wb,
    const float* __restrict__ b_out, float* __restrict__ out)
{
    __shared__ __align__(16) __hip_bfloat16 As[128 * 32];
    __shared__ __align__(16) __hip_bfloat16 Bs[128 * 32];
    const int m0 = blockIdx.y * 128, n0 = blockIdx.x * 128;
    const int tid = threadIdx.x;
    const int w = tid >> 6, l = tid & 63;
    const int wm = w >> 1, wn = w & 1;
    f32x4 acc[4][4] = {};

    for (int k0 = 0; k0 < 512; k0 += 32) {
        __syncthreads();
#pragma unroll
        for (int r = 0; r < 2; ++r) {
            int idx = r * 256 + tid;              // 0..511 chunks of 8
            int row = idx >> 2, col = (idx & 3) * 8;
            *(bf16x8*)(&As[idx * 8]) = *(const bf16x8*)(H_all + (size_t)(m0 + row) * 512 + k0 + col);
            if constexpr (PRE) {
                *(bf16x8*)(&Bs[idx * 8]) = *(const bf16x8*)(Wb + (size_t)(n0 + row) * 512 + k0 + col);
            } else {
                const float* src = W_out + (size_t)(n0 + row) * 512 + k0 + col;
                float4 f0 = *(const float4*)(src);
                float4 f1 = *(const float4*)(src + 4);
                __align__(16) __hip_bfloat16 tmp[8];
                tmp[0] = __float2bfloat16(f0.x); tmp[1] = __float2bfloat16(f0.y);
                tmp[2] = __float2bfloat16(f0.z); tmp[3] = __float2bfloat16(f0.w);
                tmp[4] = __float2bfloat16(f1.x); tmp[5] = __float2bfloat16(f1.y);
                tmp[6] = __float2bfloat16(f1.z); tmp[7] = __float2bfloat16(f1.w);
                *(bf16x8*)(&Bs[idx * 8]) = *(const bf16x8*)tmp;
            }
        }
        __syncthreads();
        bf16x8 a[4], bb[4];
#pragma unroll
        for (int i = 0; i < 4; ++i) {
            a[i]  = *(const bf16x8*)(&As[(wm * 64 + i * 16 + (l & 15)) * 32 + (l >> 4) * 8]);
            bb[i] = *(const bf16x8*)(&Bs[(wn * 64 + i * 16 + (l & 15)) * 32 + (l >> 4) * 8]);
        }
#pragma unroll
        for (int mi = 0; mi < 4; ++mi)
#pragma unroll
            for (int ni = 0; ni < 4; ++ni)
                acc[mi][ni] = __builtin_amdgcn_mfma_f32_16x16x32_bf16(a[mi], bb[ni], acc[mi][ni], 0, 0, 0);
    }

#pragma unroll
    for (int mi = 0; mi < 4; ++mi)
#pragma unroll
        for (int ni = 0; ni < 4; ++ni)
#pragma unroll
            for (int r = 0; r < 4; ++r) {
                int m = m0 + wm * 64 + mi * 16 + (l >> 4) * 4 + r;
                int n = n0 + wn * 64 + ni * 16 + (l & 15);
                out[(size_t)m * VOCAB + n] = acc[mi][ni][r] + b_out[n];
            }
}

// ---------------------------------------------------------------------------
// log_softmax in place: one block per row of 32000
// ---------------------------------------------------------------------------
__global__ __launch_bounds__(256) void lsm_kernel(float* __restrict__ out)
{
    const int r = blockIdx.x;
    float* row = out + (size_t)r * VOCAB;
    const int tid = threadIdx.x;
    __shared__ float red[8];

    float mx = -3.4e38f;
    for (int i = tid; i < VOCAB / 4; i += 256) {
        float4 v = ((const float4*)row)[i];
        mx = fmaxf(mx, fmaxf(fmaxf(v.x, v.y), fmaxf(v.z, v.w)));
    }
    for (int o = 32; o > 0; o >>= 1) mx = fmaxf(mx, __shfl_down(mx, o, 64));
    if ((tid & 63) == 0) red[tid >> 6] = mx;
    __syncthreads();
    if (tid == 0) red[4] = fmaxf(fmaxf(red[0], red[1]), fmaxf(red[2], red[3]));
    __syncthreads();
    mx = red[4];

    float sum = 0.f;
    for (int i = tid; i < VOCAB / 4; i += 256) {
        float4 v = ((const float4*)row)[i];
        sum += __expf(v.x - mx) + __expf(v.y - mx) + __expf(v.z - mx) + __expf(v.w - mx);
    }
    for (int o = 32; o > 0; o >>= 1) sum += __shfl_down(sum, o, 64);
    if ((tid & 63) == 0) red[tid >> 6] = sum;
    __syncthreads();
    if (tid == 0) red[5] = red[0] + red[1] + red[2] + red[3];
    __syncthreads();
    const float lse = mx + __logf(red[5]);

    for (int i = tid; i < VOCAB / 4; i += 256) {
        float4 v = ((float4*)row)[i];
        v.x -= lse; v.y -= lse; v.z -= lse; v.w -= lse;
        ((float4*)row)[i] = v;
    }
}

// ---------------------------------------------------------------------------
extern "C" void kernel_launch(void* const* d_in, const int* in_sizes, int n_in,
                              void* d_out, int out_size, void* d_ws, size_t ws_size,
                              hipStream_t stream)
{
    const int*   inputs     = (const int*)d_in[0];
    const float* hidden     = (const float*)d_in[1];
    // d_in[2] = batch_size (unused, fixed 64)
    const float* embedding  = (const float*)d_in[3];
    const float* W_i2h      = (const float*)d_in[4];
    const float* b_i2h      = (const float*)d_in[5];
    const float* W_h2h      = (const float*)d_in[6];
    const float* b_h2h      = (const float*)d_in[7];
    const float* W_h2a      = (const float*)d_in[8];
    const float* b_h2a      = (const float*)d_in[9];
    const float* W_h2s      = (const float*)d_in[10];
    const float* b_h2s      = (const float*)d_in[11];
    const float* W_s2h      = (const float*)d_in[12];
    const float* b_s2h      = (const float*)d_in[13];
    const float* W_out      = (const float*)d_in[14];
    const float* b_out      = (const float*)d_in[15];
    const float* empty_elem = (const float*)d_in[16];
    float* out = (float*)d_out;

    char* ws = (char*)d_ws;
    float*          hidF   = (float*)(ws + OFF_HIDF);
    float*          stacks = (float*)(ws + OFF_STACKS);
    __hip_bfloat16* Xhi    = (__hip_bfloat16*)(ws + OFF_XHI);
    __hip_bfloat16* Xlo    = (__hip_bfloat16*)(ws + OFF_XLO);
    __hip_bfloat16* WcatHi = (__hip_bfloat16*)(ws + OFF_WCATHI);
    __hip_bfloat16* WcatLo = (__hip_bfloat16*)(ws + OFF_WCATLO);
    __hip_bfloat16* H_all  = (__hip_bfloat16*)(ws + OFF_HALL);
    __hip_bfloat16* Wb     = (__hip_bfloat16*)(ws + OFF_WOUTB);
    float* out_tail = out + (size_t)SEQL * BATCH * VOCAB;
    const bool pre = (ws_size >= (size_t)WS_NEED_PRE);  // constant per session

    prep_kernel<<<2048, 256, 0, stream>>>(inputs, hidden, embedding, W_i2h, W_h2h,
                                          W_s2h, empty_elem, WcatHi, WcatLo,
                                          Xhi, Xlo, hidF, stacks);
    if (pre)
        wout_bf16_kernel<<<2048, 256, 0, stream>>>(W_out, Wb);
    for (int t = 0; t < SEQL; ++t)
        step_kernel<<<80, 256, 0, stream>>>(t, inputs, embedding, W_h2a, b_h2a,
                                            W_h2s, b_h2s, b_i2h, b_h2h, b_s2h,
                                            empty_elem, WcatHi, WcatLo, hidF, stacks,
                                            Xhi, Xlo, H_all, out_tail);
    if (pre)
        gemm_out_kernel<true><<<dim3(250, 32), 256, 0, stream>>>(H_all, W_out, Wb, b_out, out);
    else
        gemm_out_kernel<false><<<dim3(250, 32), 256, 0, stream>>>(H_all, W_out, Wb, b_out, out);
    lsm_kernel<<<4096, 256, 0, stream>>>(out);
}